// Round 3
// baseline (612.872 us; speedup 1.0000x reference)
//
#include <hip/hip_runtime.h>

#define THREADS 256

__device__ __forceinline__ float dot4f(float4 a, float4 b) {
  return a.x*b.x + a.y*b.y + a.z*b.z + a.w*b.w;
}

// One block = one sample. x_i: [28][28], W: [512][28], b: [512]
// H = sigmoid(x W^T + b) : [28][512]  (thread t owns columns t and t+256, in regs)
// G = H H^T accumulated over two 28x256 LDS chunks; Y = G^{-1} x (Gauss-Jordan)
// X = x exactly (H full row-rank => H pinv(H) = I)
// B = H^T Y : [512][28], staged+flushed in two 256x28 halves (reusing Hs chunk).
//
// Hs chunk layout (swizzled): element (r, c) c in [0,256) lives at
//   r*256 + (((c>>2) ^ (r&7))<<2) + (c&3)
__global__ __launch_bounds__(THREADS, 4) void elm_kernel(
    const float* __restrict__ x, const float* __restrict__ W,
    const float* __restrict__ bias, float* __restrict__ Xout,
    float* __restrict__ Bout)
{
  __shared__ float Hs[28*256];     // 28672 B: H chunk / B staging [256][28]
  __shared__ float xsb[28*36];     // x rows (phase1..solve), then Y^T[c][a] at c*36+a
  __shared__ float Gc[28*32];      // G[a][c] at a*32+c
  __shared__ float scratchD[14*4]; // diagonal-tile half-1 partials

  const int tid = threadIdx.x;
  const int n   = blockIdx.x;
  const float* xi = x + (size_t)n * 784;

  // ---- load x into LDS + X output = copy of x ----
  if (tid < 196) {
    const float4 v = reinterpret_cast<const float4*>(xi)[tid];
    reinterpret_cast<float4*>(Xout + (size_t)n * 784)[tid] = v;
    const int r = tid / 7, c4 = tid - r * 7;
    reinterpret_cast<float4*>(xsb)[r*9 + c4] = v;
  }
  __syncthreads();

  // ---- H = sigmoid(x W^T + b): both owned columns into registers ----
  float hc0[28], hc1[28];
  {
    float w0[28], w1[28];
    const float4* W4 = reinterpret_cast<const float4*>(W);
#pragma unroll
    for (int j4 = 0; j4 < 7; ++j4) {
      const float4 v0 = W4[tid*7 + j4];
      const float4 v1 = W4[(tid+256)*7 + j4];
      w0[4*j4+0]=v0.x; w0[4*j4+1]=v0.y; w0[4*j4+2]=v0.z; w0[4*j4+3]=v0.w;
      w1[4*j4+0]=v1.x; w1[4*j4+1]=v1.y; w1[4*j4+2]=v1.z; w1[4*j4+3]=v1.w;
    }
    const float b0 = bias[tid], b1 = bias[tid+256];
#pragma unroll 4
    for (int r = 0; r < 28; ++r) {
      const float4* xr4 = reinterpret_cast<const float4*>(&xsb[r*36]);
      float a0 = b0, a1 = b1;
#pragma unroll
      for (int j4 = 0; j4 < 7; ++j4) {
        const float4 xv = xr4[j4];
        a0 += xv.x*w0[4*j4] + xv.y*w0[4*j4+1] + xv.z*w0[4*j4+2] + xv.w*w0[4*j4+3];
        a1 += xv.x*w1[4*j4] + xv.y*w1[4*j4+1] + xv.z*w1[4*j4+2] + xv.w*w1[4*j4+3];
      }
      hc0[r] = 1.0f / (1.0f + __expf(-a0));
      hc1[r] = 1.0f / (1.0f + __expf(-a1));
    }
  }

  // ---- G tile decode (105 upper-tri 2x2 tiles x 2 granule-halves = 210 threads) ----
  int ta = 0, tc = 0;
  {
    int rem = (tid < 210) ? (tid >= 105 ? tid - 105 : tid) : 0;
    while (rem >= 14 - ta) { rem -= 14 - ta; ++ta; }
    tc = ta + rem;
  }
  const int half = (tid >= 105) ? 1 : 0;
  const int r0 = 2*ta, r1 = 2*ta+1, q0 = 2*tc, q1 = 2*tc+1;
  const int ba0 = r0*64, ba1 = r1*64, bc0 = q0*64, bc1 = q1*64;
  const int sa0 = r0&7,  sa1 = r1&7,  sc0 = q0&7,  sc1 = q1&7;
  const int hb = half << 5;
  float s00 = 0.f, s01 = 0.f, s10 = 0.f, s11 = 0.f;

  const int tg = tid >> 2, tl = tid & 3;

  auto writeChunk = [&](const float (&hc)[28]) {
#pragma unroll
    for (int r = 0; r < 28; ++r)
      Hs[r*256 + ((tg ^ (r&7)) << 2) + tl] = hc[r];
  };
  auto accumG = [&]() {
    const float4* H4 = reinterpret_cast<const float4*>(Hs);
#pragma unroll 4
    for (int i = 0; i < 32; ++i) {
      const int hg = hb + ((i + tid) & 31);     // per-lane phase rotation
      const float4 av0 = H4[ba0 + (hg ^ sa0)];
      const float4 av1 = H4[ba1 + (hg ^ sa1)];
      const float4 cv0 = H4[bc0 + (hg ^ sc0)];
      const float4 cv1 = H4[bc1 + (hg ^ sc1)];
      s00 += dot4f(av0, cv0);
      s01 += dot4f(av0, cv1);
      s10 += dot4f(av1, cv0);
      s11 += dot4f(av1, cv1);
    }
  };

  // ---- G pass 0: columns [0,256) ----
  writeChunk(hc0);
  __syncthreads();
  if (tid < 210) accumG();
  __syncthreads();

  // ---- G pass 1: columns [256,512) ----
  writeChunk(hc1);
  __syncthreads();
  if (tid < 210) {
    accumG();
    if (half == 0) {
      Gc[r0*32 + q0] = s00; Gc[r0*32 + q1] = s01;
      Gc[r1*32 + q0] = s10; Gc[r1*32 + q1] = s11;
    } else if (ta != tc) {            // store transposed (lower region)
      Gc[q0*32 + r0] = s00; Gc[q1*32 + r0] = s01;
      Gc[q0*32 + r1] = s10; Gc[q1*32 + r1] = s11;
    } else {                          // diagonal tile: tiny scratch
      scratchD[ta*4+0] = s00; scratchD[ta*4+1] = s01;
      scratchD[ta*4+2] = s10; scratchD[ta*4+3] = s11;
    }
  }
  __syncthreads();

  // ---- G combine: sum the two halves, mirror symmetric ----
  if (tid < 105) {
    int rem = tid, ua = 0;
    while (rem >= 14 - ua) { rem -= 14 - ua; ++ua; }
    const int uc = ua + rem;
    const int a0 = 2*ua, a1 = 2*ua+1, c0 = 2*uc, c1 = 2*uc+1;
    if (ua != uc) {
      const float u00 = Gc[a0*32+c0], u01 = Gc[a0*32+c1];
      const float u10 = Gc[a1*32+c0], u11 = Gc[a1*32+c1];
      const float l00 = Gc[c0*32+a0], l01 = Gc[c1*32+a0];
      const float l10 = Gc[c0*32+a1], l11 = Gc[c1*32+a1];
      const float t00 = u00+l00, t01 = u01+l01, t10 = u10+l10, t11 = u11+l11;
      Gc[a0*32+c0] = t00; Gc[a0*32+c1] = t01;
      Gc[a1*32+c0] = t10; Gc[a1*32+c1] = t11;
      Gc[c0*32+a0] = t00; Gc[c1*32+a0] = t01;
      Gc[c0*32+a1] = t10; Gc[c1*32+a1] = t11;
    } else {
      Gc[a0*32+c0] += scratchD[ua*4+0];
      Gc[a0*32+c1] += scratchD[ua*4+1];
      Gc[a1*32+c0] += scratchD[ua*4+2];
      Gc[a1*32+c1] += scratchD[ua*4+3];
    }
  }
  __syncthreads();

  // ---- solve G Y = x : Gauss-Jordan on wave 0, lane j owns augmented col j ----
  if (tid < 64) {
    const int j = tid;
    float col[28];
#pragma unroll
    for (int r = 0; r < 28; ++r) {
      float v = 0.f;
      if (j < 28)       v = Gc[r*32 + j];
      else if (j < 56)  v = xsb[r*36 + (j - 28)];
      col[r] = v;
    }
#pragma unroll
    for (int k = 0; k < 28; ++k) {
      const float piv    = __shfl(col[k], k);
      const float pivinv = 1.0f / piv;
      col[k] *= pivinv;
#pragma unroll
      for (int r = 0; r < 28; ++r) {
        if (r == k) continue;
        const float m = __shfl(col[r], k);
        col[r] -= m * col[k];
      }
    }
    if (j >= 28 && j < 56) {          // write Y^T: Yt[c][a] = Y[a][c]
      const int c = j - 28;
#pragma unroll
      for (int r = 0; r < 28; ++r) xsb[c*36 + r] = col[r];
    }
  }
  __syncthreads();   // Hs free from here (G passes done) -> reuse as B staging

  // ---- B = H^T Y, two halves: stage [256][28] in LDS, coalesced flush ----
  auto bPass = [&](const float (&hc)[28], float* BObase) {
    float* Bs = Hs;
#pragma unroll
    for (int c4 = 0; c4 < 7; ++c4) {
      float av[4];
#pragma unroll
      for (int cc = 0; cc < 4; ++cc) {
        const int c = 4*c4 + cc;
        const float4* y4 = reinterpret_cast<const float4*>(&xsb[c*36]);
        float acc = 0.f;
#pragma unroll
        for (int a4 = 0; a4 < 7; ++a4) {
          const float4 yv = y4[a4];
          acc += hc[4*a4]*yv.x + hc[4*a4+1]*yv.y + hc[4*a4+2]*yv.z + hc[4*a4+3]*yv.w;
        }
        av[cc] = acc;
      }
      float4 A; A.x=av[0]; A.y=av[1]; A.z=av[2]; A.w=av[3];
      *reinterpret_cast<float4*>(&Bs[tid*28 + 4*c4]) = A;
    }
    __syncthreads();
    const float4* Bs4 = reinterpret_cast<const float4*>(Hs);
    float4* BO4 = reinterpret_cast<float4*>(BObase);
#pragma unroll
    for (int k = 0; k < 7; ++k) BO4[k*256 + tid] = Bs4[k*256 + tid];
  };

  float* Bbase = Bout + (size_t)n * 14336;
  bPass(hc0, Bbase);          // rows [0,256)
  __syncthreads();            // flush reads done before restage
  bPass(hc1, Bbase + 7168);   // rows [256,512)
}

extern "C" void kernel_launch(void* const* d_in, const int* in_sizes, int n_in,
                              void* d_out, int out_size, void* d_ws, size_t ws_size,
                              hipStream_t stream) {
  const float* x = (const float*)d_in[0];
  const float* W = (const float*)d_in[1];
  const float* b = (const float*)d_in[2];
  const int N = in_sizes[0] / 784;              // 4096 samples
  float* Xout = (float*)d_out;                  // [N,1,28,28]
  float* Bout = Xout + (size_t)N * 784;         // [N,1,512,28]
  elm_kernel<<<N, THREADS, 0, stream>>>(x, W, b, Xout, Bout);
}

// Round 4
// 283.919 us; speedup vs baseline: 2.1586x; 2.1586x over previous
//
#include <hip/hip_runtime.h>

#define THREADS 512

__device__ __forceinline__ float dot4f(float4 a, float4 b) {
  return a.x*b.x + a.y*b.y + a.z*b.z + a.w*b.w;
}

// One block = one sample; 512 threads, thread t owns H column t.
// H = sigmoid(x W^T + b) : [28][512]
// G = H H^T (105 2x2 tiles x 4 h-quarters = 420 threads, partials via LDS)
// Y = G^{-1} x (Gauss-Jordan, wave 0);  X = x exactly;  B = H^T Y staged+flushed.
//
// Hs layout (swizzled): element (r,h) at  r*512 + (((h>>2) ^ (r&7))<<2) + (h&3)
__global__ __launch_bounds__(THREADS, 4) void elm_kernel(
    const float* __restrict__ x, const float* __restrict__ W,
    const float* __restrict__ bias, float* __restrict__ Xout,
    float* __restrict__ Bout)
{
  __shared__ float Hs[28*512];   // 57344 B: H / G-partial scratch / B staging
  __shared__ float xsb[28*36];   // 4032 B: x rows, then Y^T[c][a] at c*36+a
  __shared__ float Gc[28*32];    // 3584 B: G[a][c] at a*32+c
  // total 64960 B -> 2 blocks/CU

  const int tid = threadIdx.x;
  const int n   = blockIdx.x;
  const float* xi = x + (size_t)n * 784;

  // ---- 1. load x into LDS + X output = copy of x ----
  if (tid < 196) {
    const float4 v = reinterpret_cast<const float4*>(xi)[tid];
    reinterpret_cast<float4*>(Xout + (size_t)n * 784)[tid] = v;
    const int r = tid / 7, c4 = tid - r * 7;
    reinterpret_cast<float4*>(xsb)[r*9 + c4] = v;
  }
  __syncthreads();

  // ---- 2. H = sigmoid(x W^T + b): one column per thread, regs + swizzled LDS ----
  float hc[28];
  {
    float w[28];
    const float4* W4 = reinterpret_cast<const float4*>(W);
#pragma unroll
    for (int j4 = 0; j4 < 7; ++j4) {
      const float4 v = W4[tid*7 + j4];
      w[4*j4+0]=v.x; w[4*j4+1]=v.y; w[4*j4+2]=v.z; w[4*j4+3]=v.w;
    }
    const float bv = bias[tid];
    const int tg = tid >> 2, tl = tid & 3;
#pragma unroll 4
    for (int r = 0; r < 28; ++r) {
      const float4* xr4 = reinterpret_cast<const float4*>(&xsb[r*36]);
      float a = bv;
#pragma unroll
      for (int j4 = 0; j4 < 7; ++j4) {
        const float4 xv = xr4[j4];
        a += xv.x*w[4*j4] + xv.y*w[4*j4+1] + xv.z*w[4*j4+2] + xv.w*w[4*j4+3];
      }
      const float h = 1.0f / (1.0f + __expf(-a));
      hc[r] = h;
      Hs[r*512 + ((tg ^ (r&7)) << 2) + tl] = h;
    }
  }
  __syncthreads();

  // ---- 3. G partials: 105 upper-tri 2x2 tiles x 4 h-quarters = 420 threads ----
  const bool gact = (tid < 420);
  int tile = 0, ta = 0, tc = 0;
  float s00 = 0.f, s01 = 0.f, s10 = 0.f, s11 = 0.f;
  int r0 = 0, r1 = 1, q0 = 0, q1 = 1;
  if (gact) {
    const int q = tid / 105;
    tile = tid - 105*q;
    int rem = tile;
    while (rem >= 14 - ta) { rem -= 14 - ta; ++ta; }
    tc = ta + rem;
    r0 = 2*ta; r1 = r0+1; q0 = 2*tc; q1 = q0+1;
    const int ba0 = r0*128, ba1 = r1*128, bc0 = q0*128, bc1 = q1*128;
    const int sa0 = r0&7,   sa1 = r1&7,   sc0 = q0&7,   sc1 = q1&7;
    const int hb  = q << 5;
    const float4* H4 = reinterpret_cast<const float4*>(Hs);
#pragma unroll 4
    for (int i = 0; i < 32; ++i) {
      const int hg = hb + ((i + tid) & 31);   // per-lane phase rotation
      const float4 av0 = H4[ba0 + (hg ^ sa0)];
      const float4 av1 = H4[ba1 + (hg ^ sa1)];
      const float4 cv0 = H4[bc0 + (hg ^ sc0)];
      const float4 cv1 = H4[bc1 + (hg ^ sc1)];
      s00 += dot4f(av0, cv0);
      s01 += dot4f(av0, cv1);
      s10 += dot4f(av1, cv0);
      s11 += dot4f(av1, cv1);
    }
  }
  __syncthreads();               // all H reads done -> Hs reusable as scratch

  // ---- 4. exchange partials through Hs[0..6720) : [tile][q][4] ----
  if (gact) {
    const int q = tid / 105;
    float4 p; p.x = s00; p.y = s01; p.z = s10; p.w = s11;
    *reinterpret_cast<float4*>(&Hs[tile*16 + q*4]) = p;
  }
  __syncthreads();

  // ---- 5. combine 4 partials, write G + mirror ----
  if (tid < 105) {               // for tid<105: q==0, ta/tc/r0../q1 already valid
    const float4 p0 = *reinterpret_cast<const float4*>(&Hs[tid*16 +  0]);
    const float4 p1 = *reinterpret_cast<const float4*>(&Hs[tid*16 +  4]);
    const float4 p2 = *reinterpret_cast<const float4*>(&Hs[tid*16 +  8]);
    const float4 p3 = *reinterpret_cast<const float4*>(&Hs[tid*16 + 12]);
    const float t00 = p0.x+p1.x+p2.x+p3.x;
    const float t01 = p0.y+p1.y+p2.y+p3.y;
    const float t10 = p0.z+p1.z+p2.z+p3.z;
    const float t11 = p0.w+p1.w+p2.w+p3.w;
    Gc[r0*32+q0] = t00; Gc[r0*32+q1] = t01;
    Gc[r1*32+q0] = t10; Gc[r1*32+q1] = t11;
    Gc[q0*32+r0] = t00; Gc[q1*32+r0] = t01;   // mirror (diag: same, harmless)
    Gc[q0*32+r1] = t10; Gc[q1*32+r1] = t11;
  }
  __syncthreads();

  // ---- 6. solve G Y = x : Gauss-Jordan on wave 0, lane j owns augmented col j ----
  if (tid < 64) {
    const int j = tid;
    float col[28];
#pragma unroll
    for (int r = 0; r < 28; ++r) {
      float v = 0.f;
      if (j < 28)       v = Gc[r*32 + j];
      else if (j < 56)  v = xsb[r*36 + (j - 28)];
      col[r] = v;
    }
#pragma unroll
    for (int k = 0; k < 28; ++k) {
      const float piv    = __shfl(col[k], k);
      const float pivinv = 1.0f / piv;
      col[k] *= pivinv;
#pragma unroll
      for (int r = 0; r < 28; ++r) {
        if (r == k) continue;
        const float m = __shfl(col[r], k);
        col[r] -= m * col[k];
      }
    }
    if (j >= 28 && j < 56) {     // write Y^T: Yt[c][a] = Y[a][c]
      const int c = j - 28;
#pragma unroll
      for (int r = 0; r < 28; ++r) xsb[c*36 + r] = col[r];
    }
  }
  __syncthreads();

  // ---- 7. B = H^T Y : one row per thread from register hc; stage in Hs ----
  {
#pragma unroll
    for (int c4 = 0; c4 < 7; ++c4) {
      float av[4];
#pragma unroll
      for (int cc = 0; cc < 4; ++cc) {
        const float4* y4 = reinterpret_cast<const float4*>(&xsb[(4*c4+cc)*36]);
        float acc = 0.f;
#pragma unroll
        for (int a4 = 0; a4 < 7; ++a4) {
          const float4 yv = y4[a4];
          acc += hc[4*a4]*yv.x + hc[4*a4+1]*yv.y + hc[4*a4+2]*yv.z + hc[4*a4+3]*yv.w;
        }
        av[cc] = acc;
      }
      float4 A; A.x = av[0]; A.y = av[1]; A.z = av[2]; A.w = av[3];
      *reinterpret_cast<float4*>(&Hs[tid*28 + 4*c4]) = A;
    }
  }
  __syncthreads();

  // ---- 8. coalesced flush of B: 3584 float4 ----
  {
    const float4* Bs4 = reinterpret_cast<const float4*>(Hs);
    float4* BO4 = reinterpret_cast<float4*>(Bout + (size_t)n * 14336);
#pragma unroll
    for (int k = 0; k < 7; ++k) BO4[k*512 + tid] = Bs4[k*512 + tid];
  }
}

extern "C" void kernel_launch(void* const* d_in, const int* in_sizes, int n_in,
                              void* d_out, int out_size, void* d_ws, size_t ws_size,
                              hipStream_t stream) {
  const float* x = (const float*)d_in[0];
  const float* W = (const float*)d_in[1];
  const float* b = (const float*)d_in[2];
  const int N = in_sizes[0] / 784;              // 4096 samples
  float* Xout = (float*)d_out;                  // [N,1,28,28]
  float* Bout = Xout + (size_t)N * 784;         // [N,1,512,28]
  elm_kernel<<<N, THREADS, 0, stream>>>(x, W, b, Xout, Bout);
}